// Round 7
// baseline (467.338 us; speedup 1.0000x reference)
//
#include <hip/hip_runtime.h>
#include <hip/hip_bf16.h>
#include <hip/hip_fp16.h>

#define EMB 64
#define SCAN_CHUNK 1024   // 256 threads x 4 elems per scan block

// ---- dtype-flexible loads ---------------------------------------------------
__device__ __forceinline__ float ld_elem(const void* p, long long i, int bf) {
    if (bf) return (float)((const __hip_bfloat16*)p)[i];
    return ((const float*)p)[i];
}
__device__ __forceinline__ float ld_x0(const void* uw, const void* iw,
                                       int n_user_elems, long long elem, int bf) {
    if (elem < (long long)n_user_elems) return ld_elem(uw, elem, bf);
    return ld_elem(iw, elem - n_user_elems, bf);
}

// ---- nontemporal helpers ----------------------------------------------------
__device__ __forceinline__ float2 ldnt_f2(const float2* p) {
    unsigned long long u = __builtin_nontemporal_load((const unsigned long long*)p);
    float2 r;
    r.x = __uint_as_float((unsigned)u);
    r.y = __uint_as_float((unsigned)(u >> 32));
    return r;
}
__device__ __forceinline__ unsigned short f32_to_bf16_bits(float f) {
    unsigned int u = __float_as_uint(f);
    unsigned int lsb = (u >> 16) & 1u;
    u += 0x7FFFu + lsb;               // round-to-nearest-even
    return (unsigned short)(u >> 16);
}
__device__ __forceinline__ void stnt_u16(unsigned short v, unsigned short* p) {
    __builtin_nontemporal_store(v, p);
}

// ---- histogram + fused dtype probe -----------------------------------------
__global__ void hist_rows(const int* __restrict__ rows, int* __restrict__ counts, int nnz,
                          const unsigned short* __restrict__ v16, int* __restrict__ flag) {
    int tid = blockIdx.x * blockDim.x + threadIdx.x;
    int stride = gridDim.x * blockDim.x;
    for (int e = tid; e < nnz; e += stride) atomicAdd(&counts[rows[e]], 1);
    if (tid == 0) {
        int hits = 0;
        for (int i = 0; i < 256; ++i) {
            unsigned int hb = v16[i] >> 8;
            unsigned int ex = hb & 0x7F;
            if (hb < 0x80 && ex >= 0x30 && ex < 0x40) hits++;
        }
        *flag = (hits >= 200) ? 1 : 0;   // 1 = bf16, 0 = fp32
    }
}

// ---- scan phase 1: per-block exclusive scan + block sums -------------------
__global__ void scan_blocks(const int* __restrict__ in, int* __restrict__ excl,
                            int* __restrict__ blocksums, int n) {
    __shared__ int lds[256];
    int base = blockIdx.x * SCAN_CHUNK;
    int t = threadIdx.x;
    int c[4]; int s = 0;
    for (int k = 0; k < 4; ++k) {
        int i = base + t * 4 + k;
        c[k] = (i < n) ? in[i] : 0;
        s += c[k];
    }
    lds[t] = s;
    __syncthreads();
    for (int off = 1; off < 256; off <<= 1) {
        int v = lds[t];
        int add = (t >= off) ? lds[t - off] : 0;
        __syncthreads();
        lds[t] = v + add;
        __syncthreads();
    }
    int run = (t > 0) ? lds[t - 1] : 0;
    if (t == 255) blocksums[blockIdx.x] = lds[255];
    for (int k = 0; k < 4; ++k) {
        int i = base + t * 4 + k;
        if (i < n) excl[i] = run;
        run += c[k];
    }
}

// ---- scan phase 2 (fused): every block re-scans blocksums in LDS, fixes up --
__global__ void scan_fixup(int* __restrict__ excl, const int* __restrict__ bsums,
                           int* __restrict__ offs, int n, int nrows, int nb) {
    __shared__ int lds[256];
    int t = threadIdx.x;
    lds[t] = (t < nb) ? bsums[t] : 0;
    __syncthreads();
    for (int off = 1; off < 256; off <<= 1) {
        int v = lds[t];
        int add = (t >= off) ? lds[t - off] : 0;
        __syncthreads();
        lds[t] = v + add;
        __syncthreads();
    }
    __syncthreads();
    int i = blockIdx.x * blockDim.x + threadIdx.x;
    if (i >= n) return;
    int b = i / SCAN_CHUNK;
    int v = excl[i] + (b > 0 ? lds[b - 1] : 0);
    excl[i] = v;                 // excl becomes row_ptr
    if (i < nrows) offs[i] = v;  // scatter cursors
}

// ---- scatter edges into row-sorted packed (val,col) records ----------------
__global__ void scatter_edges(const void* __restrict__ vals, const int* __restrict__ rows,
                              const int* __restrict__ cols, int* __restrict__ offs,
                              float2* __restrict__ edges, int nnz,
                              const int* __restrict__ flagp) {
    int e = blockIdx.x * blockDim.x + threadIdx.x;
    if (e >= nnz) return;
    int bf = *flagp;
    float v = ld_elem(vals, e, bf);
    int r = rows[e];
    int pos = atomicAdd(&offs[r], 1);
    float2 rec; rec.x = v; rec.y = __int_as_float(cols[e]);
    edges[pos] = rec;
}

// ---- gather-only SpMM: TWO rows per wave, dual 4-deep MLP pipelines --------
// GMODE: 0 = gather x0 (inputs, dtype via flag), 1 = gather fp16 g
// OMODE: 1 = write g' = x0 + acc as fp16, 3 = final (x0+acc)*0.25 (dtype via flag)
template <int GMODE, int OMODE>
__global__ void spmm_csr(const int* __restrict__ row_ptr,
                         const float2* __restrict__ edges,
                         const void* __restrict__ uw, const void* __restrict__ iw,
                         int n_user_elems,
                         const __half* __restrict__ gin, void* __restrict__ gout,
                         int nrows, int nnz, const int* __restrict__ flagp) {
    int pid  = (blockIdx.x * blockDim.x + threadIdx.x) >> 6;
    int lane = threadIdx.x & 63;
    int r0 = pid * 2;
    if (r0 >= nrows) return;
    int r1 = r0 + 1;
    bool has1 = (r1 < nrows);
    int bf = *flagp;

    int b0  = row_ptr[r0];
    int e0r = row_ptr[r0 + 1];
    int b1  = e0r;
    int e1r = has1 ? row_ptr[r1 + 1] : e0r;
    int n0 = e0r - b0, n1 = e1r - b1;
    int l0 = e0r - 1; if (l0 < 0) l0 = 0;   // clamp target: last edge of row
    int l1 = e1r - 1; if (l1 < 0) l1 = 0;
    int nmax = (n0 > n1) ? n0 : n1;
    float acc0 = 0.f, acc1 = 0.f;

#define GATHER(E, XD) { \
        long long ce = (long long)__float_as_int((E).y) * EMB + lane; \
        if (GMODE == 0) XD = ld_x0(uw, iw, n_user_elems, ce, bf); \
        else            XD = __half2float(gin[ce]); }

    for (int k = 0; k < nmax; k += 4) {
        float2 E0[4], E1[4];
#pragma unroll
        for (int q = 0; q < 4; ++q) {
            int j0 = b0 + k + q; j0 = (j0 < l0) ? j0 : l0; j0 = (j0 > 0) ? j0 : 0;
            int j1 = b1 + k + q; j1 = (j1 < l1) ? j1 : l1; j1 = (j1 > 0) ? j1 : 0;
            E0[q] = ldnt_f2(edges + j0);
            E1[q] = ldnt_f2(edges + j1);
        }
        float X0[4], X1[4];
#pragma unroll
        for (int q = 0; q < 4; ++q) { GATHER(E0[q], X0[q]); GATHER(E1[q], X1[q]); }
#pragma unroll
        for (int q = 0; q < 4; ++q) {
            float w0 = (k + q < n0) ? E0[q].x : 0.f;
            float w1 = (k + q < n1) ? E1[q].x : 0.f;
            acc0 += w0 * X0[q];
            acc1 += w1 * X1[q];
        }
    }
#undef GATHER

    long long re0 = (long long)r0 * EMB + lane;
    long long re1 = re0 + EMB;
    float x00 = ld_x0(uw, iw, n_user_elems, re0, bf);
    float x01 = has1 ? ld_x0(uw, iw, n_user_elems, re1, bf) : 0.f;
    unsigned short* g16 = (unsigned short*)gout;
    if (OMODE == 1) {
        stnt_u16(__half_as_ushort(__float2half(x00 + acc0)), g16 + re0);
        if (has1) stnt_u16(__half_as_ushort(__float2half(x01 + acc1)), g16 + re1);
    } else {
        float o0 = (x00 + acc0) * 0.25f;
        float o1 = (x01 + acc1) * 0.25f;
        if (bf) {
            stnt_u16(f32_to_bf16_bits(o0), g16 + re0);
            if (has1) stnt_u16(f32_to_bf16_bits(o1), g16 + re1);
        } else {
            __builtin_nontemporal_store(o0, ((float*)gout) + re0);
            if (has1) __builtin_nontemporal_store(o1, ((float*)gout) + re1);
        }
    }
}

extern "C" void kernel_launch(void* const* d_in, const int* in_sizes, int n_in,
                              void* d_out, int out_size, void* d_ws, size_t ws_size,
                              hipStream_t stream) {
    const void* uw   = d_in[0];
    const void* iw   = d_in[1];
    const void* vals = d_in[2];
    const int*  rows = (const int*)d_in[3];
    const int*  cols = (const int*)d_in[4];

    const int n_user = in_sizes[0];                // 6.4M elems
    const int total  = in_sizes[0] + in_sizes[1];  // 12.8M elems
    const int nnz    = in_sizes[2];                // 1M edges
    const int nrows  = total / EMB;                // 200K

    // ---- workspace layout (256B-aligned) ----
    char* p = (char*)d_ws;
    auto alloc = [&](size_t bytes) { char* q = p; p += (bytes + 255) & ~(size_t)255; return q; };
    int*    flag    = (int*)   alloc(sizeof(int));
    int*    row_ptr = (int*)   alloc((size_t)(nrows + 1) * sizeof(int));
    int*    counts  = (int*)   alloc((size_t)(nrows + 1) * sizeof(int));
    int*    offs    = (int*)   alloc((size_t)nrows * sizeof(int));
    int*    bsums   = (int*)   alloc(1024 * sizeof(int));
    float2* edges   = (float2*)alloc((size_t)nnz * sizeof(float2));
    size_t used = (size_t)(p - (char*)d_ws);
    size_t avail = (ws_size > used) ? ws_size - used : 0;

    const size_t g_f16 = (size_t)total * sizeof(__half);  // 25.6 MB
    __half *g2, *g3;
    if (avail >= 2 * g_f16 + 512) { g2 = (__half*)alloc(g_f16); g3 = (__half*)alloc(g_f16); }
    else { g2 = (__half*)d_out; g3 = (__half*)alloc(g_f16); }  // d_out dead-staged, overwritten at end

    // ---- CSR build (every call; capture-safe) ----
    (void)hipMemsetAsync(counts, 0, (size_t)(nrows + 1) * sizeof(int), stream);
    const int hb = (nnz / 4 + 255) / 256;
    hist_rows<<<hb, 256, 0, stream>>>(rows, counts, nnz, (const unsigned short*)vals, flag);
    const int n_scan = nrows + 1;
    const int nb = (n_scan + SCAN_CHUNK - 1) / SCAN_CHUNK;   // 196 <= 256
    scan_blocks<<<nb, 256, 0, stream>>>(counts, row_ptr, bsums, n_scan);
    scan_fixup<<<(n_scan + 255) / 256, 256, 0, stream>>>(row_ptr, bsums, offs, n_scan, nrows, nb);
    const int eb = (nnz + 255) / 256;
    scatter_edges<<<eb, 256, 0, stream>>>(vals, rows, cols, offs, edges, nnz, flag);

    // ---- 3 gather-only SpMM layers (Horner), fp16 inter-layer staging ----
    const int npairs = (nrows + 1) / 2;
    const int rb = (int)(((long long)npairs * 64 + 255) / 256);   // one wave per row-pair
    spmm_csr<0, 1><<<rb, 256, 0, stream>>>(row_ptr, edges, uw, iw, n_user,
                                           nullptr, g2, nrows, nnz, flag);
    spmm_csr<1, 1><<<rb, 256, 0, stream>>>(row_ptr, edges, uw, iw, n_user,
                                           g2, g3, nrows, nnz, flag);
    spmm_csr<1, 3><<<rb, 256, 0, stream>>>(row_ptr, edges, uw, iw, n_user,
                                           g3, d_out, nrows, nnz, flag);
}

// Round 8
// 436.748 us; speedup vs baseline: 1.0700x; 1.0700x over previous
//
#include <hip/hip_runtime.h>
#include <hip/hip_bf16.h>
#include <hip/hip_fp16.h>

#define EMB 64
#define SCAN_CHUNK 1024   // 256 threads x 4 elems per scan block

// ---- dtype-flexible scalar loads (build kernels) ---------------------------
__device__ __forceinline__ float ld_elem(const void* p, long long i, int bf) {
    if (bf) return (float)((const __hip_bfloat16*)p)[i];
    return ((const float*)p)[i];
}

// ---- nontemporal / pack helpers --------------------------------------------
__device__ __forceinline__ float2 ldnt_f2(const float2* p) {
    unsigned long long u = __builtin_nontemporal_load((const unsigned long long*)p);
    float2 r;
    r.x = __uint_as_float((unsigned)u);
    r.y = __uint_as_float((unsigned)(u >> 32));
    return r;
}
__device__ __forceinline__ unsigned short f32_to_bf16_bits(float f) {
    unsigned int u = __float_as_uint(f);
    unsigned int lsb = (u >> 16) & 1u;
    u += 0x7FFFu + lsb;               // round-to-nearest-even
    return (unsigned short)(u >> 16);
}

// ---- histogram + fused dtype probe -----------------------------------------
__global__ void hist_rows(const int* __restrict__ rows, int* __restrict__ counts, int nnz,
                          const unsigned short* __restrict__ v16, int* __restrict__ flag) {
    int tid = blockIdx.x * blockDim.x + threadIdx.x;
    int stride = gridDim.x * blockDim.x;
    for (int e = tid; e < nnz; e += stride) atomicAdd(&counts[rows[e]], 1);
    if (tid == 0) {
        int hits = 0;
        for (int i = 0; i < 256; ++i) {
            unsigned int hb = v16[i] >> 8;
            unsigned int ex = hb & 0x7F;
            if (hb < 0x80 && ex >= 0x30 && ex < 0x40) hits++;
        }
        *flag = (hits >= 200) ? 1 : 0;   // 1 = bf16, 0 = fp32
    }
}

// ---- scan phase 1: per-block exclusive scan + block sums -------------------
__global__ void scan_blocks(const int* __restrict__ in, int* __restrict__ excl,
                            int* __restrict__ blocksums, int n) {
    __shared__ int lds[256];
    int base = blockIdx.x * SCAN_CHUNK;
    int t = threadIdx.x;
    int c[4]; int s = 0;
    for (int k = 0; k < 4; ++k) {
        int i = base + t * 4 + k;
        c[k] = (i < n) ? in[i] : 0;
        s += c[k];
    }
    lds[t] = s;
    __syncthreads();
    for (int off = 1; off < 256; off <<= 1) {
        int v = lds[t];
        int add = (t >= off) ? lds[t - off] : 0;
        __syncthreads();
        lds[t] = v + add;
        __syncthreads();
    }
    int run = (t > 0) ? lds[t - 1] : 0;
    if (t == 255) blocksums[blockIdx.x] = lds[255];
    for (int k = 0; k < 4; ++k) {
        int i = base + t * 4 + k;
        if (i < n) excl[i] = run;
        run += c[k];
    }
}

// ---- scan phase 2 (fused): every block re-scans blocksums in LDS, fixes up --
__global__ void scan_fixup(int* __restrict__ excl, const int* __restrict__ bsums,
                           int* __restrict__ offs, int n, int nrows, int nb) {
    __shared__ int lds[256];
    int t = threadIdx.x;
    lds[t] = (t < nb) ? bsums[t] : 0;
    __syncthreads();
    for (int off = 1; off < 256; off <<= 1) {
        int v = lds[t];
        int add = (t >= off) ? lds[t - off] : 0;
        __syncthreads();
        lds[t] = v + add;
        __syncthreads();
    }
    __syncthreads();
    int i = blockIdx.x * blockDim.x + threadIdx.x;
    if (i >= n) return;
    int b = i / SCAN_CHUNK;
    int v = excl[i] + (b > 0 ? lds[b - 1] : 0);
    excl[i] = v;                 // excl becomes row_ptr
    if (i < nrows) offs[i] = v;  // scatter cursors
}

// ---- scatter edges into row-sorted packed (val,col) records ----------------
__global__ void scatter_edges(const void* __restrict__ vals, const int* __restrict__ rows,
                              const int* __restrict__ cols, int* __restrict__ offs,
                              float2* __restrict__ edges, int nnz,
                              const int* __restrict__ flagp) {
    int e = blockIdx.x * blockDim.x + threadIdx.x;
    if (e >= nnz) return;
    int bf = *flagp;
    float v = ld_elem(vals, e, bf);
    int r = rows[e];
    int pos = atomicAdd(&offs[r], 1);
    float2 rec; rec.x = v; rec.y = __int_as_float(cols[e]);
    edges[pos] = rec;
}

// ---- gather-only SpMM: one wave per row, HALF-WAVE dual-edge gathers -------
// lanes 0-31 (h=0): even edges; lanes 32-63 (h=1): odd edges.
// each lane covers dim pair {2d, 2d+1}; halves combined via shfl_xor(32).
// GMODE: 0 = gather x0 (inputs, dtype via flag), 1 = gather fp16 g
// OMODE: 1 = write g' = x0 + acc as fp16, 3 = final (x0+acc)*0.25 (dtype via flag)
template <int GMODE, int OMODE>
__global__ __launch_bounds__(256) void spmm_csr(
        const int* __restrict__ row_ptr,
        const float2* __restrict__ edges,
        const void* __restrict__ uw, const void* __restrict__ iw,
        int n_user_elems,
        const unsigned short* __restrict__ gin, void* __restrict__ gout,
        int nrows, const int* __restrict__ flagp) {
    int wid  = (blockIdx.x * blockDim.x + threadIdx.x) >> 6;
    int lane = threadIdx.x & 63;
    int h = lane >> 5;          // which edge of the pair
    int d = lane & 31;          // dim pair index
    if (wid >= nrows) return;
    int bf = *flagp;
    int b = row_ptr[wid], e = row_ptr[wid + 1];
    int n = e - b;
    float ax = 0.f, ay = 0.f;

    if (n > 0) {
        int last = e - 1;
        int nsteps = (n + 1) >> 1;                 // edge pairs
        for (int s = 0; s < nsteps; s += 4) {
            float2 E[4]; float w[4];
#pragma unroll
            for (int q = 0; q < 4; ++q) {
                int t2 = 2 * (s + q) + h;
                int j = b + t2;
                j = (j <= last) ? j : last;        // clamp: same-line dup, weight 0
                E[q] = ldnt_f2(edges + j);
                w[q] = (t2 < n) ? E[q].x : 0.f;
            }
            float gx[4], gy[4];
#pragma unroll
            for (int q = 0; q < 4; ++q) {
                long long ce = (long long)__float_as_int(E[q].y) * EMB + 2 * d;
                if (GMODE == 1) {
                    unsigned u = *(const unsigned*)(gin + ce);
                    gx[q] = __half2float(__ushort_as_half((unsigned short)u));
                    gy[q] = __half2float(__ushort_as_half((unsigned short)(u >> 16)));
                } else {
                    if (bf) {
                        const unsigned short* p;
                        long long idx;
                        if (ce < (long long)n_user_elems) { p = (const unsigned short*)uw; idx = ce; }
                        else { p = (const unsigned short*)iw; idx = ce - n_user_elems; }
                        unsigned u = *(const unsigned*)(p + idx);
                        gx[q] = __uint_as_float(u << 16);
                        gy[q] = __uint_as_float(u & 0xFFFF0000u);
                    } else {
                        const float* p;
                        long long idx;
                        if (ce < (long long)n_user_elems) { p = (const float*)uw; idx = ce; }
                        else { p = (const float*)iw; idx = ce - n_user_elems; }
                        float2 v = *(const float2*)(p + idx);
                        gx[q] = v.x; gy[q] = v.y;
                    }
                }
            }
#pragma unroll
            for (int q = 0; q < 4; ++q) { ax += w[q] * gx[q]; ay += w[q] * gy[q]; }
        }
    }
    // combine even/odd-edge halves (both halves end with the full sum)
    ax += __shfl_xor(ax, 32, 64);
    ay += __shfl_xor(ay, 32, 64);

    if (h == 0) {
        long long re = (long long)wid * EMB + 2 * d;
        float x0x, x0y;
        if (bf) {
            const unsigned short* p; long long idx;
            if (re < (long long)n_user_elems) { p = (const unsigned short*)uw; idx = re; }
            else { p = (const unsigned short*)iw; idx = re - n_user_elems; }
            unsigned u = *(const unsigned*)(p + idx);
            x0x = __uint_as_float(u << 16);
            x0y = __uint_as_float(u & 0xFFFF0000u);
        } else {
            const float* p; long long idx;
            if (re < (long long)n_user_elems) { p = (const float*)uw; idx = re; }
            else { p = (const float*)iw; idx = re - n_user_elems; }
            float2 v = *(const float2*)(p + idx);
            x0x = v.x; x0y = v.y;
        }
        float ox = x0x + ax, oy = x0y + ay;
        if (OMODE == 1) {
            unsigned u = (unsigned)__half_as_ushort(__float2half(ox)) |
                         ((unsigned)__half_as_ushort(__float2half(oy)) << 16);
            __builtin_nontemporal_store(u, (unsigned*)((unsigned short*)gout + re));
        } else {
            ox *= 0.25f; oy *= 0.25f;
            if (bf) {
                unsigned u = (unsigned)f32_to_bf16_bits(ox) |
                             ((unsigned)f32_to_bf16_bits(oy) << 16);
                __builtin_nontemporal_store(u, (unsigned*)((unsigned short*)gout + re));
            } else {
                float2 v; v.x = ox; v.y = oy;
                __builtin_nontemporal_store(v.x, ((float*)gout) + re);
                __builtin_nontemporal_store(v.y, ((float*)gout) + re + 1);
            }
        }
    }
}

extern "C" void kernel_launch(void* const* d_in, const int* in_sizes, int n_in,
                              void* d_out, int out_size, void* d_ws, size_t ws_size,
                              hipStream_t stream) {
    const void* uw   = d_in[0];
    const void* iw   = d_in[1];
    const void* vals = d_in[2];
    const int*  rows = (const int*)d_in[3];
    const int*  cols = (const int*)d_in[4];

    const int n_user = in_sizes[0];                // 6.4M elems
    const int total  = in_sizes[0] + in_sizes[1];  // 12.8M elems
    const int nnz    = in_sizes[2];                // 1M edges
    const int nrows  = total / EMB;                // 200K

    // ---- workspace layout (256B-aligned) ----
    char* p = (char*)d_ws;
    auto alloc = [&](size_t bytes) { char* q = p; p += (bytes + 255) & ~(size_t)255; return q; };
    int*    flag    = (int*)   alloc(sizeof(int));
    int*    row_ptr = (int*)   alloc((size_t)(nrows + 1) * sizeof(int));
    int*    counts  = (int*)   alloc((size_t)(nrows + 1) * sizeof(int));
    int*    offs    = (int*)   alloc((size_t)nrows * sizeof(int));
    int*    bsums   = (int*)   alloc(1024 * sizeof(int));
    float2* edges   = (float2*)alloc((size_t)nnz * sizeof(float2));
    size_t used = (size_t)(p - (char*)d_ws);
    size_t avail = (ws_size > used) ? ws_size - used : 0;

    const size_t g_f16 = (size_t)total * sizeof(__half);  // 25.6 MB
    unsigned short *g2, *g3;
    if (avail >= 2 * g_f16 + 512) { g2 = (unsigned short*)alloc(g_f16); g3 = (unsigned short*)alloc(g_f16); }
    else { g2 = (unsigned short*)d_out; g3 = (unsigned short*)alloc(g_f16); }  // d_out dead-staged, overwritten at end

    // ---- CSR build (every call; capture-safe) ----
    (void)hipMemsetAsync(counts, 0, (size_t)(nrows + 1) * sizeof(int), stream);
    const int hb = (nnz / 4 + 255) / 256;
    hist_rows<<<hb, 256, 0, stream>>>(rows, counts, nnz, (const unsigned short*)vals, flag);
    const int n_scan = nrows + 1;
    const int nb = (n_scan + SCAN_CHUNK - 1) / SCAN_CHUNK;   // 196 <= 256
    scan_blocks<<<nb, 256, 0, stream>>>(counts, row_ptr, bsums, n_scan);
    scan_fixup<<<(n_scan + 255) / 256, 256, 0, stream>>>(row_ptr, bsums, offs, n_scan, nrows, nb);
    const int eb = (nnz + 255) / 256;
    scatter_edges<<<eb, 256, 0, stream>>>(vals, rows, cols, offs, edges, nnz, flag);

    // ---- 3 gather-only SpMM layers (Horner), fp16 inter-layer staging ----
    const int rb = (int)(((long long)nrows * 64 + 255) / 256);   // one wave per row
    spmm_csr<0, 1><<<rb, 256, 0, stream>>>(row_ptr, edges, uw, iw, n_user,
                                           nullptr, g2, nrows, flag);
    spmm_csr<1, 1><<<rb, 256, 0, stream>>>(row_ptr, edges, uw, iw, n_user,
                                           g2, g3, nrows, flag);
    spmm_csr<1, 3><<<rb, 256, 0, stream>>>(row_ptr, edges, uw, iw, n_user,
                                           g3, d_out, nrows, flag);
}